// Round 7
// baseline (69.858 us; speedup 1.0000x reference)
//
#include <hip/hip_runtime.h>
#include <float.h>
#include <math.h>

#define NB 32
#define LD 512
#define LP 4096
#define HD 128
#define PV 26
// ws layout (float index):
//   cnt     int[NB]        @ 0      (memset to 0 every call, 128 B)
//   ws_m    float[256]     @ 32
//   ws_den  float[256]     @ 288
//   ws_col  float[256*32]  @ 544
//   ws_part float[256*128] @ 8736
//   ws_hist int[256*32]    @ 41504

// One kernel: 256 blocks x 512 threads. Block (b,chunk) computes phase A
// (scores, masked row-softmax locals, chunk colmax, chunk hist, d_vec partial
// from in-register A fragments). The 8th finisher per batch (device-scope
// ticket) runs phase B (chunk merge, protein softmax, p_vec, MLP) in-block.
__global__ __launch_bounds__(512)
void k_fused(const int* __restrict__ drug_ids, const int* __restrict__ prot_ids,
             const float* __restrict__ drug_emb, const float* __restrict__ prot_emb,
             const float* __restrict__ W1, const float* __restrict__ b1,
             const float* __restrict__ W2, const float* __restrict__ b2,
             float* __restrict__ out, float* __restrict__ wsf) {
    int*   cnt     = (int*)wsf;
    float* ws_m    = wsf + 32;
    float* ws_den  = wsf + 288;
    float* ws_col  = wsf + 544;
    float* ws_part = wsf + 8736;
    int*   ws_hist = (int*)(wsf + 41504);

    int t = threadIdx.x;
    int wid = t >> 6, lane = t & 63;
    int b = blockIdx.x >> 3, chunk = blockIdx.x & 7;
    int q = __builtin_amdgcn_readfirstlane(wid);
    int l = chunk * 64 + lane;

    __shared__ float red[8][64][27];   // 55.3 KB
    __shared__ float ev[64];
    __shared__ unsigned wor[8];
    __shared__ int hist[32];
    __shared__ int lastFlag;
    __shared__ float sscale[8], ew[32], comb[2 * HD], hpart[4][64];
    __shared__ float sInvD, sInvP;

    // ---------------- Phase A ----------------
    if (t < 32) hist[t] = 0;

    // presence mask over all 4096 ids (8/thread)
    const int4* pid4 = reinterpret_cast<const int4*>(prot_ids + b * LP);
    int4 i0 = pid4[t], i1 = pid4[t + 512];
    unsigned pm = (1u << i0.x) | (1u << i0.y) | (1u << i0.z) | (1u << i0.w)
                | (1u << i1.x) | (1u << i1.y) | (1u << i1.z) | (1u << i1.w);
    #pragma unroll
    for (int off = 32; off; off >>= 1) pm |= __shfl_xor(pm, off, 64);
    if (lane == 0) wor[q] = pm;

    // A sixteenth-row preload (16 k-floats; reused for d_vec partial)
    const float* __restrict__ A =
        drug_emb + (size_t)drug_ids[b * LD + l] * HD + q * 16;
    float4 a[4];
    #pragma unroll
    for (int i = 0; i < 4; ++i) a[i] = reinterpret_cast<const float4*>(A)[i];

    __syncthreads();   // hist zeroed

    // own-slice histogram (512 ids, 1/thread)
    atomicAdd(&hist[prot_ids[b * LP + chunk * 512 + t]], 1);

    const float* __restrict__ Bq = prot_emb + q * 16;
    float s[PV];
    #pragma unroll
    for (int v = 0; v < PV; ++v) s[v] = 0.f;
    #pragma unroll
    for (int i = 0; i < 4; ++i) {
        float4 av = a[i];
        #pragma unroll
        for (int v = 0; v < PV; ++v) {
            float4 p = reinterpret_cast<const float4*>(Bq + v * HD)[i];
            s[v] = fmaf(av.x, p.x, fmaf(av.y, p.y,
                   fmaf(av.z, p.z, fmaf(av.w, p.w, s[v]))));
        }
    }
    #pragma unroll
    for (int v = 0; v < PV; ++v) red[q][lane][v] = s[v];
    __syncthreads();

    unsigned msk = wor[0] | wor[1] | wor[2] | wor[3]
                 | wor[4] | wor[5] | wor[6] | wor[7];

    // K-reduce 8 slices
    for (int o = t; o < 64 * PV; o += 512) {
        int l2 = o / PV, v = o - l2 * PV;
        red[0][l2][v] = red[0][l2][v] + red[1][l2][v] + red[2][l2][v]
                      + red[3][l2][v] + red[4][l2][v] + red[5][l2][v]
                      + red[6][l2][v] + red[7][l2][v];
    }
    __syncthreads();

    if (wid == 0) {
        float r = -FLT_MAX;
        #pragma unroll
        for (int v = 0; v < PV; ++v)
            if ((msk >> v) & 1) r = fmaxf(r, red[0][lane][v]);
        float m = r;
        #pragma unroll
        for (int off = 32; off; off >>= 1) m = fmaxf(m, __shfl_xor(m, off, 64));
        float e = __expf(r - m);
        ev[lane] = e;
        float den = e;
        #pragma unroll
        for (int off = 32; off; off >>= 1) den += __shfl_xor(den, off, 64);
        if (lane == 0) {
            ws_m[(b << 3) + chunk] = m;
            ws_den[(b << 3) + chunk] = den;
        }
    } else if (wid == 1 && lane < PV) {
        float cmx = -FLT_MAX;
        for (int r = 0; r < 64; ++r) cmx = fmaxf(cmx, red[0][r][lane]);
        ws_col[((b << 3) + chunk) * 32 + lane] = cmx;
    }
    __syncthreads();

    // d_vec partial: red[q][lane][c] = e_lane * a_c  (h = q*16+c)
    float myE = ev[lane];
    #pragma unroll
    for (int i = 0; i < 4; ++i) {
        red[q][lane][4 * i + 0] = myE * a[i].x;
        red[q][lane][4 * i + 1] = myE * a[i].y;
        red[q][lane][4 * i + 2] = myE * a[i].z;
        red[q][lane][4 * i + 3] = myE * a[i].w;
    }
    __syncthreads();

    if (t < 128) {
        int qq = t >> 4, c = t & 15;
        float sum = 0.f;
        for (int r = 0; r < 64; ++r) sum += red[qq][r][c];
        ws_part[((b << 3) + chunk) * 128 + qq * 16 + c] = sum;
    }
    if (t < 32) ws_hist[((b << 3) + chunk) * 32 + t] = hist[t];

    // ---------------- Completion ticket ----------------
    __threadfence();            // release this block's ws writes (device scope)
    __syncthreads();            // all threads' writes + fences done
    if (t == 0) lastFlag = (atomicAdd(&cnt[b], 1) == 7);
    __syncthreads();
    if (!lastFlag) return;
    __threadfence();            // acquire: see the other 7 blocks' ws writes

    // ---------------- Phase B (8th finisher only) ----------------
    if (t < 8) {
        float m = ws_m[(b << 3) + t];
        float M = m;
        #pragma unroll
        for (int off = 4; off; off >>= 1) M = fmaxf(M, __shfl_xor(M, off, 8));
        float sc = __expf(m - M);
        float dd = sc * ws_den[(b << 3) + t];
        float D = dd;
        #pragma unroll
        for (int off = 4; off; off >>= 1) D += __shfl_xor(D, off, 8);
        sscale[t] = sc;
        if (t == 0) sInvD = 1.f / D;
    } else if (wid == 1) {
        int v = lane;
        float cmx = -FLT_MAX; int c = 0;
        if (v < PV) {
            #pragma unroll
            for (int c8 = 0; c8 < 8; ++c8) {
                cmx = fmaxf(cmx, ws_col[((b << 3) + c8) * 32 + v]);
                c += ws_hist[((b << 3) + c8) * 32 + v];
            }
        }
        float m0 = (c > 0) ? cmx : -FLT_MAX;
        float M2 = m0;
        #pragma unroll
        for (int off = 32; off; off >>= 1) M2 = fmaxf(M2, __shfl_xor(M2, off, 64));
        float w = (c > 0) ? (float)c * __expf(cmx - M2) : 0.f;
        float S = w;
        #pragma unroll
        for (int off = 32; off; off >>= 1) S += __shfl_xor(S, off, 64);
        if (v < 32) ew[v] = (v < PV) ? w : 0.f;
        if (lane == 0) sInvP = 1.f / S;
    }
    __syncthreads();

    if (t < HD) {
        float d = 0.f;
        #pragma unroll
        for (int c8 = 0; c8 < 8; ++c8)
            d = fmaf(sscale[c8], ws_part[((b << 3) + c8) * 128 + t], d);
        comb[t] = d * sInvD;
    } else if (t < 2 * HD) {
        int h = t - HD;
        float p = 0.f;
        #pragma unroll
        for (int v = 0; v < PV; ++v)
            p = fmaf(ew[v], prot_emb[v * HD + h], p);
        comb[t] = p * sInvP;
    }
    __syncthreads();

    // MLP 256->64 (4-way K split) -> relu -> 64->1
    if (t < 256) {
        int j = t & 63, seg = t >> 6;
        float acc = 0.f;
        #pragma unroll
        for (int k = 0; k < 64; ++k) {
            int kk = seg * 64 + k;
            acc = fmaf(comb[kk], W1[kk * 64 + j], acc);
        }
        hpart[seg][j] = acc;
    }
    __syncthreads();
    if (t < 64) {
        float hj = b1[t] + hpart[0][t] + hpart[1][t] + hpart[2][t] + hpart[3][t];
        hj = fmaxf(hj, 0.f);
        float o = hj * W2[t];
        #pragma unroll
        for (int off = 32; off; off >>= 1) o += __shfl_xor(o, off, 64);
        if (t == 0) out[b] = o + b2[0];
    }
}

extern "C" void kernel_launch(void* const* d_in, const int* in_sizes, int n_in,
                              void* d_out, int out_size, void* d_ws, size_t ws_size,
                              hipStream_t stream) {
    const int*   drug_ids = (const int*)d_in[0];
    const int*   prot_ids = (const int*)d_in[1];
    const float* drug_emb = (const float*)d_in[2];
    const float* prot_emb = (const float*)d_in[3];
    const float* W1 = (const float*)d_in[4];
    const float* b1 = (const float*)d_in[5];
    const float* W2 = (const float*)d_in[6];
    const float* b2 = (const float*)d_in[7];
    float* out = (float*)d_out;
    float* wsf = (float*)d_ws;

    hipMemsetAsync(d_ws, 0, NB * sizeof(int), stream);   // zero tickets
    k_fused<<<NB * 8, 512, 0, stream>>>(drug_ids, prot_ids, drug_emb, prot_emb,
                                        W1, b1, W2, b2, out, wsf);
}

// Round 8
// 16.372 us; speedup vs baseline: 4.2669x; 4.2669x over previous
//
#include <hip/hip_runtime.h>
#include <float.h>
#include <math.h>

#define NB 32
#define LD 512
#define LP 4096
#define HD 128
#define PV 26
#define MAGIC 0x13579BDF
#define QS 1733   // padded per-q LDS slice: 64*27+5 floats; 1733%32=5 -> no 8-way bank alias
// ws layout (float index):
//   flag    int[256]       @ 0      (self-resetting; never memset)
//   ws_m    float[256]     @ 256
//   ws_den  float[256]     @ 512
//   ws_col  float[256*32]  @ 768
//   ws_part float[256*128] @ 8960
//   ws_hist int[256*32]    @ 41728

__device__ __forceinline__ float aloadf(float* p) { return atomicAdd(p, 0.0f); }
__device__ __forceinline__ int   aloadi(int* p)   { return atomicAdd(p, 0); }

// One node: 256 blocks x 512 threads. Block (b,chunk) runs phase A (scores,
// masked row-softmax locals, chunk colmax, chunk hist, d_vec partial from
// in-register A fragments), publishes partials via device atomics (coherence
// point -> no fences), raises a MAGIC flag. Block (b,7) spin-waits the 7
// sibling flags, runs phase B, resets flags.
__global__ __launch_bounds__(512)
void k_fused(const int* __restrict__ drug_ids, const int* __restrict__ prot_ids,
             const float* __restrict__ drug_emb, const float* __restrict__ prot_emb,
             const float* __restrict__ W1, const float* __restrict__ b1,
             const float* __restrict__ W2, const float* __restrict__ b2,
             float* __restrict__ out, float* __restrict__ wsf) {
    int*   flag    = (int*)wsf;
    float* ws_m    = wsf + 256;
    float* ws_den  = wsf + 512;
    float* ws_col  = wsf + 768;
    float* ws_part = wsf + 8960;
    int*   ws_hist = (int*)(wsf + 41728);

    int t = threadIdx.x;
    int wid = t >> 6, lane = t & 63;
    int b = blockIdx.x >> 3, chunk = blockIdx.x & 7;
    int b8 = b << 3;
    int q = __builtin_amdgcn_readfirstlane(wid);
    int l = chunk * 64 + lane;

    __shared__ float red[8 * QS];      // 55.5 KB, q-slices bank-staggered
    __shared__ float ev[64];
    __shared__ unsigned wor[8];
    __shared__ int hist[32];
    __shared__ float sscale[8], ew[32], comb[2 * HD], hpart[4][64];
    __shared__ float sInvD, sInvP;

    // ---------------- Phase A ----------------
    if (t < 32) hist[t] = 0;

    // presence mask over all 4096 ids (8/thread)
    const int4* pid4 = reinterpret_cast<const int4*>(prot_ids + b * LP);
    int4 i0 = pid4[t], i1 = pid4[t + 512];
    unsigned pm = (1u << i0.x) | (1u << i0.y) | (1u << i0.z) | (1u << i0.w)
                | (1u << i1.x) | (1u << i1.y) | (1u << i1.z) | (1u << i1.w);
    #pragma unroll
    for (int off = 32; off; off >>= 1) pm |= __shfl_xor(pm, off, 64);
    if (lane == 0) wor[q] = pm;

    // A sixteenth-row preload (16 k-floats; reused for d_vec partial)
    const float* __restrict__ A =
        drug_emb + (size_t)drug_ids[b * LD + l] * HD + q * 16;
    float4 a[4];
    #pragma unroll
    for (int i = 0; i < 4; ++i) a[i] = reinterpret_cast<const float4*>(A)[i];

    __syncthreads();   // hist zeroed

    // own-slice histogram (512 ids, 1/thread)
    atomicAdd(&hist[prot_ids[b * LP + chunk * 512 + t]], 1);

    const float* __restrict__ Bq = prot_emb + q * 16;
    float s[PV];
    #pragma unroll
    for (int v = 0; v < PV; ++v) s[v] = 0.f;
    #pragma unroll
    for (int i = 0; i < 4; ++i) {
        float4 av = a[i];
        #pragma unroll
        for (int v = 0; v < PV; ++v) {
            float4 p = reinterpret_cast<const float4*>(Bq + v * HD)[i];
            s[v] = fmaf(av.x, p.x, fmaf(av.y, p.y,
                   fmaf(av.z, p.z, fmaf(av.w, p.w, s[v]))));
        }
    }
    #pragma unroll
    for (int v = 0; v < PV; ++v) red[q * QS + lane * 27 + v] = s[v];
    __syncthreads();

    unsigned msk = wor[0] | wor[1] | wor[2] | wor[3]
                 | wor[4] | wor[5] | wor[6] | wor[7];

    // K-reduce 8 slices into slice 0
    for (int o = t; o < 64 * PV; o += 512) {
        int l2 = o / PV, v = o - l2 * PV;
        int idx = l2 * 27 + v;
        red[idx] = red[idx]           + red[QS + idx]     + red[2 * QS + idx]
                 + red[3 * QS + idx]  + red[4 * QS + idx] + red[5 * QS + idx]
                 + red[6 * QS + idx]  + red[7 * QS + idx];
    }
    __syncthreads();

    if (wid == 0) {
        float r = -FLT_MAX;
        #pragma unroll
        for (int v = 0; v < PV; ++v)
            if ((msk >> v) & 1) r = fmaxf(r, red[lane * 27 + v]);
        float m = r;
        #pragma unroll
        for (int off = 32; off; off >>= 1) m = fmaxf(m, __shfl_xor(m, off, 64));
        float e = __expf(r - m);
        ev[lane] = e;
        float den = e;
        #pragma unroll
        for (int off = 32; off; off >>= 1) den += __shfl_xor(den, off, 64);
        if (lane == 0) {
            atomicExch(&ws_m[b8 + chunk], m);
            atomicExch(&ws_den[b8 + chunk], den);
        }
    } else if (wid == 1 && lane < PV) {
        float cmx = -FLT_MAX;
        for (int r = 0; r < 64; ++r) cmx = fmaxf(cmx, red[r * 27 + lane]);
        atomicExch(&ws_col[(b8 + chunk) * 32 + lane], cmx);
    }
    __syncthreads();

    // d_vec partial: red[q][lane][c] = e_lane * a_c  (h = q*16+c)
    float myE = ev[lane];
    #pragma unroll
    for (int i = 0; i < 4; ++i) {
        red[q * QS + lane * 27 + 4 * i + 0] = myE * a[i].x;
        red[q * QS + lane * 27 + 4 * i + 1] = myE * a[i].y;
        red[q * QS + lane * 27 + 4 * i + 2] = myE * a[i].z;
        red[q * QS + lane * 27 + 4 * i + 3] = myE * a[i].w;
    }
    __syncthreads();

    if (t < 128) {
        int qq = t >> 4, c = t & 15;
        float sum = 0.f;
        for (int r = 0; r < 64; ++r) sum += red[qq * QS + r * 27 + c];
        atomicExch(&ws_part[(b8 + chunk) * 128 + qq * 16 + c], sum);
    }
    if (t < 32) atomicExch(&ws_hist[(b8 + chunk) * 32 + t], hist[t]);

    // publish: __syncthreads() drains each wave's vmcnt before s_barrier,
    // so all atomicExch ops above are at the coherence point past this line.
    __syncthreads();
    if (chunk != 7) {
        if (t == 0) atomicExch(&flag[b8 + chunk], MAGIC);
        return;
    }

    // ---------------- Phase B (chunk-7 block only) ----------------
    if (t < 7) {
        while (aloadi(&flag[b8 + t]) != MAGIC) __builtin_amdgcn_s_sleep(1);
    }
    __syncthreads();

    if (t < 8) {
        float m = aloadf(&ws_m[b8 + t]);
        float M = m;
        #pragma unroll
        for (int off = 4; off; off >>= 1) M = fmaxf(M, __shfl_xor(M, off, 8));
        float sc = __expf(m - M);
        float dd = sc * aloadf(&ws_den[b8 + t]);
        float D = dd;
        #pragma unroll
        for (int off = 4; off; off >>= 1) D += __shfl_xor(D, off, 8);
        sscale[t] = sc;
        if (t == 0) sInvD = 1.f / D;
    } else if (wid == 1) {
        int v = lane;
        float cmx = -FLT_MAX; int c = 0;
        if (v < PV) {
            #pragma unroll
            for (int c8 = 0; c8 < 8; ++c8) {
                cmx = fmaxf(cmx, aloadf(&ws_col[(b8 + c8) * 32 + v]));
                c += aloadi(&ws_hist[(b8 + c8) * 32 + v]);
            }
        }
        float m0 = (c > 0) ? cmx : -FLT_MAX;
        float M2 = m0;
        #pragma unroll
        for (int off = 32; off; off >>= 1) M2 = fmaxf(M2, __shfl_xor(M2, off, 64));
        float w = (c > 0) ? (float)c * __expf(cmx - M2) : 0.f;
        float S = w;
        #pragma unroll
        for (int off = 32; off; off >>= 1) S += __shfl_xor(S, off, 64);
        if (v < 32) ew[v] = (v < PV) ? w : 0.f;
        if (lane == 0) sInvP = 1.f / S;
    }
    __syncthreads();

    if (t < HD) {
        float d = 0.f;
        #pragma unroll
        for (int c8 = 0; c8 < 8; ++c8)
            d = fmaf(sscale[c8], aloadf(&ws_part[(b8 + c8) * 128 + t]), d);
        comb[t] = d * sInvD;
    } else if (t < 2 * HD) {
        int h = t - HD;
        float p = 0.f;
        #pragma unroll
        for (int v = 0; v < PV; ++v)
            p = fmaf(ew[v], prot_emb[v * HD + h], p);
        comb[t] = p * sInvP;
    }
    __syncthreads();

    // MLP 256->64 (4-way K split) -> relu -> 64->1
    if (t < 256) {
        int j = t & 63, seg = t >> 6;
        float acc = 0.f;
        #pragma unroll
        for (int k = 0; k < 64; ++k) {
            int kk = seg * 64 + k;
            acc = fmaf(comb[kk], W1[kk * 64 + j], acc);
        }
        hpart[seg][j] = acc;
    }
    __syncthreads();
    if (t < 64) {
        float hj = b1[t] + hpart[0][t] + hpart[1][t] + hpart[2][t] + hpart[3][t];
        hj = fmaxf(hj, 0.f);
        float o = hj * W2[t];
        #pragma unroll
        for (int off = 32; off; off >>= 1) o += __shfl_xor(o, off, 64);
        if (t == 0) out[b] = o + b2[0];
    }
    __syncthreads();
    // self-clean flags for the next replay (no memset node needed)
    if (t < 7) atomicExch(&flag[b8 + t], 0);
}

extern "C" void kernel_launch(void* const* d_in, const int* in_sizes, int n_in,
                              void* d_out, int out_size, void* d_ws, size_t ws_size,
                              hipStream_t stream) {
    const int*   drug_ids = (const int*)d_in[0];
    const int*   prot_ids = (const int*)d_in[1];
    const float* drug_emb = (const float*)d_in[2];
    const float* prot_emb = (const float*)d_in[3];
    const float* W1 = (const float*)d_in[4];
    const float* b1 = (const float*)d_in[5];
    const float* W2 = (const float*)d_in[6];
    const float* b2 = (const float*)d_in[7];
    float* out = (float*)d_out;
    float* wsf = (float*)d_ws;

    k_fused<<<NB * 8, 512, 0, stream>>>(drug_ids, prot_ids, drug_emb, prot_emb,
                                        W1, b1, W2, b2, out, wsf);
}